// Round 13
// baseline (94.804 us; speedup 1.0000x reference)
//
#include <hip/hip_runtime.h>
#include <hip/hip_bf16.h>

// Problem constants:
//   X: (B=16, D=512, 60, 60) fp32 -> N = 3600
//   codewords: (K=32, D=512) fp32, scale: (K=32,) fp32
//   out E: (B, K, D) fp32
constexpr int BB = 16;
constexpr int DD = 512;
constexpr int NN = 3600;
constexpr int KK = 32;
constexpr int NP3 = 3648;     // padded n (57 tiles of 64)
constexpr int NTILE = 57;
constexpr int NDR1 = 4;       // K1 d-slices of 128
constexpr int NNR1 = 12;      // K1 n-ranges (tiles split by formula)
constexpr int NCH2 = 15;      // K2 n-chunks of 256
constexpr int NDR3 = 32;      // K3 d-slices of 16
constexpr int NST3 = 113;     // K3 n-steps of 32 (113*32=3616 <= NP3)

typedef __attribute__((ext_vector_type(8))) short short8;
typedef __attribute__((ext_vector_type(4))) float f32x4;

__device__ inline unsigned bf16pack(float a, float b) {
    unsigned ia = __float_as_uint(a), ib = __float_as_uint(b);
    ia = (ia + 0x7fffu + ((ia >> 16) & 1u)) >> 16;          // RNE to bf16
    ib = (ib + 0x7fffu + ((ib >> 16) & 1u)) & 0xffff0000u;
    return ia | ib;
}
__device__ inline float bf2f(ushort u) {
    return __uint_as_float(((unsigned)u) << 16);
}

// ---------------------------------------------------------------------------
// K0: Cbf[k][d] = bf16(Cw[k][d]);  sc2[k] = scale[k]*sum_d C[k,d]^2
// ---------------------------------------------------------------------------
__global__ __launch_bounds__(256) void k0_prep(const float* __restrict__ Cw,
                                               const float* __restrict__ scale,
                                               ushort* __restrict__ Cbf,
                                               float* __restrict__ sc2) {
    __shared__ float buf[8][32];
    const int t = threadIdx.x;
    const int k = t & 31;
    const int h = t >> 5;   // 0..7, 64 d's each
    const float4* row = reinterpret_cast<const float4*>(Cw + k * DD + h * 64);
    uint2* crow = reinterpret_cast<uint2*>(Cbf + k * DD + h * 64);
    float s = 0.f;
#pragma unroll
    for (int j = 0; j < 16; ++j) {
        float4 v = row[j];
        crow[j] = make_uint2(bf16pack(v.x, v.y), bf16pack(v.z, v.w));
        s += v.x * v.x + v.y * v.y + v.z * v.z + v.w * v.w;
    }
    buf[h][k] = s;
    __syncthreads();
    if (t < 32) {
        float tot = 0.f;
#pragma unroll
        for (int j = 0; j < 8; ++j) tot += buf[j][t];
        sc2[t] = scale[t] * tot;
    }
}

// ---------------------------------------------------------------------------
// K1: d-sliced GEMM1 partials. Block (b, dr of 128 d, nr of ~4-5 64-n tiles).
// Each block walks its 128 X rows strictly sequentially (n-order). No LDS,
// no barriers. Out: xcp[b][dr][k][n] bf16 partial xc over 128 d; x2 partials.
// Grid: 16*4*12 = 768 blocks x 256 threads (4 independent waves).
// ---------------------------------------------------------------------------
__global__ __launch_bounds__(256) void k1_gemm1(const float* __restrict__ X,
                                                const ushort* __restrict__ Cbf,
                                                ushort* __restrict__ xcp,
                                                float* __restrict__ x2p) {
    const int t = threadIdx.x;
    const int w = t >> 6;
    const int l = t & 63;
    const int q = l >> 4;     // 0..3
    const int r = l & 15;     // 0..15
    const int bid = blockIdx.x;
    const int nr = bid % NNR1;
    const int dr = (bid / NNR1) % NDR1;
    const int b = bid / (NNR1 * NDR1);
    const int t0 = (NTILE * nr) / NNR1;
    const int t1 = (NTILE * (nr + 1)) / NNR1;

    const float* Xbase = X + ((size_t)b * DD + dr * 128 + q * 8) * NN;

    // C fragments for this d-slice (fixed across tiles)
    short8 cf0[4], cf1[4];
#pragma unroll
    for (int s = 0; s < 4; ++s) {
        cf0[s] = *reinterpret_cast<const short8*>(Cbf + r * DD + dr * 128 + s * 32 + q * 8);
        cf1[s] = *reinterpret_cast<const short8*>(Cbf + (r + 16) * DD + dr * 128 + s * 32 + q * 8);
    }

    ushort* xcb0 = xcp + (((size_t)b * NDR1 + dr) * KK + r) * NP3;
    ushort* xcb1 = xcb0 + (size_t)16 * NP3;
    float* x2b = x2p + ((size_t)b * NDR1 + dr) * NP3;

#pragma unroll 2
    for (int tl = t0; tl < t1; ++tl) {
        const int nb = tl * 64 + w * 16;
        int nc = nb + r;
        if (nc > NN - 1) nc = NN - 1;
        const float* Xp = Xbase + nc;

        f32x4 acc0 = {0.f, 0.f, 0.f, 0.f};
        f32x4 acc1 = {0.f, 0.f, 0.f, 0.f};
        float x2a = 0.f;
#pragma unroll
        for (int s = 0; s < 4; ++s) {
            float xv[8];
#pragma unroll
            for (int j = 0; j < 8; ++j) xv[j] = Xp[(size_t)(s * 32 + j) * NN];
#pragma unroll
            for (int j = 0; j < 8; ++j) x2a = fmaf(xv[j], xv[j], x2a);
            union { short8 s8; unsigned u[4]; } a;
            a.u[0] = bf16pack(xv[0], xv[1]);
            a.u[1] = bf16pack(xv[2], xv[3]);
            a.u[2] = bf16pack(xv[4], xv[5]);
            a.u[3] = bf16pack(xv[6], xv[7]);
            acc0 = __builtin_amdgcn_mfma_f32_16x16x32_bf16(a.s8, cf0[s], acc0, 0, 0, 0);
            acc1 = __builtin_amdgcn_mfma_f32_16x16x32_bf16(a.s8, cf1[s], acc1, 0, 0, 0);
        }
        // x2 partial (sum over this block's 128 d): reduce the 4 q-groups
        float x2f = x2a;
        x2f += __shfl_xor(x2f, 16);
        x2f += __shfl_xor(x2f, 32);
        if (l < 16) x2b[nb + l] = x2f;

        // xcp writes: lane (q,r) holds n = nb+4q+i for k=r (+16)
        *reinterpret_cast<uint2*>(xcb0 + nb + 4 * q) =
            make_uint2(bf16pack(acc0[0], acc0[1]), bf16pack(acc0[2], acc0[3]));
        *reinterpret_cast<uint2*>(xcb1 + nb + 4 * q) =
            make_uint2(bf16pack(acc1[0], acc1[1]), bf16pack(acc1[2], acc1[3]));
    }
}

// ---------------------------------------------------------------------------
// K2: reduce xc partials + softmax -> At[b][k][n] bf16 (coalesced via LDS
// transpose) + Asum block partials. Grid: 16*15 = 240 blocks x 256 threads,
// thread t owns n = blk*256 + t.
// ---------------------------------------------------------------------------
__global__ __launch_bounds__(256) void k2_softmax(const ushort* __restrict__ xcp,
                                                  const float* __restrict__ x2p,
                                                  const float* __restrict__ scale,
                                                  const float* __restrict__ sc2,
                                                  ushort* __restrict__ At,
                                                  float* __restrict__ asum_part) {
    __shared__ ushort As[256][36];   // pad 36: uint-aligned rows, 2-way banks
    __shared__ float red[8][32];

    const int t = threadIdx.x;
    const int blk = blockIdx.x % NCH2;
    const int b = blockIdx.x / NCH2;
    const int n0 = blk * 256;
    const int n = n0 + t;
    const int nc = (n < NP3) ? n : (NP3 - 1);

    float x2 = 0.f;
#pragma unroll
    for (int dr = 0; dr < NDR1; ++dr)
        x2 += x2p[((size_t)b * NDR1 + dr) * NP3 + nc];

    float xc[KK];
#pragma unroll
    for (int k = 0; k < KK; ++k) xc[k] = 0.f;
#pragma unroll
    for (int dr = 0; dr < NDR1; ++dr) {
        const ushort* base = xcp + ((size_t)b * NDR1 + dr) * KK * NP3 + nc;
#pragma unroll
        for (int k = 0; k < KK; ++k) xc[k] += bf2f(base[(size_t)k * NP3]);
    }

    // softmax (exact, registers)
    float sl[KK];
    float m = -1e30f;
#pragma unroll
    for (int k = 0; k < KK; ++k) {
        const float sk = scale[k];
        sl[k] = fmaf(sk, x2, sc2[k]) - 2.f * sk * xc[k];
        m = fmaxf(m, sl[k]);
    }
    float sum = 0.f;
#pragma unroll
    for (int k = 0; k < KK; ++k) {
        sl[k] = __expf(sl[k] - m);
        sum += sl[k];
    }
    const float inv = 1.f / sum;
#pragma unroll
    for (int k = 0; k < KK; ++k) sl[k] *= inv;
    if (n >= NN) {
#pragma unroll
        for (int k = 0; k < KK; ++k) sl[k] = 0.f;
    }

    // stash row in LDS (bf16, uint stores)
#pragma unroll
    for (int p = 0; p < 16; ++p)
        *reinterpret_cast<unsigned*>(&As[t][2 * p]) = bf16pack(sl[2 * p], sl[2 * p + 1]);
    __syncthreads();

    // Asum partials
    {
        const int g = t >> 5, k = t & 31;
        float s = 0.f;
#pragma unroll
        for (int i = 0; i < 32; ++i) s += bf2f(As[g * 32 + i][k]);
        red[g][k] = s;
    }
    __syncthreads();
    if (t < KK) {
        float s = 0.f;
#pragma unroll
        for (int g = 0; g < 8; ++g) s += red[g][t];
        asum_part[((size_t)b * NCH2 + blk) * KK + t] = s;
    }

    // At out: row k = j, coalesced 512B stores per instruction
    if (n0 + t < NP3) {
#pragma unroll
        for (int j = 0; j < KK; ++j)
            At[((size_t)b * KK + j) * NP3 + n0 + t] = As[t][j];
    }
}

// ---------------------------------------------------------------------------
// K3: d-sliced GEMM2, direct E. Block (b, dr of 16 d) loops ALL n (waves
// split the n-steps 4 ways, LDS-reduced). X rows walked sequentially.
// Grid: 16*32 = 512 blocks x 256 threads.
// ---------------------------------------------------------------------------
__global__ __launch_bounds__(256) void k3_gemm2(const float* __restrict__ X,
                                                const ushort* __restrict__ At,
                                                const float* __restrict__ asum_part,
                                                const float* __restrict__ Cw,
                                                float* __restrict__ E) {
    __shared__ float redL[4][512];
    __shared__ float asum_l[KK];

    const int t = threadIdx.x;
    const int w = t >> 6;
    const int l = t & 63;
    const int q = l >> 4;
    const int r = l & 15;
    const int dr = blockIdx.x & 31;
    const int b = blockIdx.x >> 5;

    if (t < KK) {
        float s = 0.f;
#pragma unroll
        for (int j = 0; j < NCH2; ++j)
            s += asum_part[((size_t)b * NCH2 + j) * KK + t];
        asum_l[t] = s;
    }

    const int d = dr * 16 + r;
    const float* Xp = X + ((size_t)b * DD + d) * NN;
    const ushort* a0p = At + ((size_t)b * KK + r) * NP3;
    const ushort* a1p = a0p + (size_t)16 * NP3;

    const int s0 = (NST3 * w) / 4;
    const int s1 = (NST3 * (w + 1)) / 4;

    f32x4 acc0 = {0.f, 0.f, 0.f, 0.f};
    f32x4 acc1 = {0.f, 0.f, 0.f, 0.f};

#pragma unroll 2
    for (int s = s0; s < s1; ++s) {
        int off = s * 32 + q * 8;
        if (off > NN - 8) off = NN - 8;   // At==0 beyond 3600 (8 | 3600)
        const float4 f0 = *reinterpret_cast<const float4*>(Xp + off);
        const float4 f1 = *reinterpret_cast<const float4*>(Xp + off + 4);
        union { short8 s8; unsigned u[4]; } bb;
        bb.u[0] = bf16pack(f0.x, f0.y);
        bb.u[1] = bf16pack(f0.z, f0.w);
        bb.u[2] = bf16pack(f1.x, f1.y);
        bb.u[3] = bf16pack(f1.z, f1.w);
        const short8 a0 = *reinterpret_cast<const short8*>(a0p + s * 32 + q * 8);
        const short8 a1 = *reinterpret_cast<const short8*>(a1p + s * 32 + q * 8);
        acc0 = __builtin_amdgcn_mfma_f32_16x16x32_bf16(a0, bb.s8, acc0, 0, 0, 0);
        acc1 = __builtin_amdgcn_mfma_f32_16x16x32_bf16(a1, bb.s8, acc1, 0, 0, 0);
    }

    // D[row=k-local][col=d-local]: stash per-wave partials
#pragma unroll
    for (int i = 0; i < 4; ++i) {
        redL[w][(q * 4 + i) * 16 + r] = acc0[i];
        redL[w][(16 + q * 4 + i) * 16 + r] = acc1[i];
    }
    __syncthreads();

    if (t < 128) {
        const int k = t >> 2;
        const int dq = t & 3;
        f32x4 s4 = {0.f, 0.f, 0.f, 0.f};
#pragma unroll
        for (int jw = 0; jw < 4; ++jw) {
            const f32x4 v = *reinterpret_cast<const f32x4*>(&redL[jw][k * 16 + dq * 4]);
            s4[0] += v[0]; s4[1] += v[1]; s4[2] += v[2]; s4[3] += v[3];
        }
        const float asum = asum_l[k];
        const float4 c = *reinterpret_cast<const float4*>(Cw + k * DD + dr * 16 + dq * 4);
        float4 o;
        o.x = s4[0] - asum * c.x;
        o.y = s4[1] - asum * c.y;
        o.z = s4[2] - asum * c.z;
        o.w = s4[3] - asum * c.w;
        *reinterpret_cast<float4*>(E + ((size_t)b * KK + k) * DD + dr * 16 + dq * 4) = o;
    }
}

// ---------------------------------------------------------------------------
extern "C" void kernel_launch(void* const* d_in, const int* in_sizes, int n_in,
                              void* d_out, int out_size, void* d_ws, size_t ws_size,
                              hipStream_t stream) {
    const float* X     = (const float*)d_in[0];
    const float* Cw    = (const float*)d_in[1];
    const float* scale = (const float*)d_in[2];
    float* E = (float*)d_out;

    // ws layout (float slots):
    //   xcp  : 16*4*32*3648 ushort = 3,735,552 float slots  (14.9 MB)
    //   x2p  : 16*4*3648 float     =   233,472
    //   At   : 16*32*3648 ushort   =   933,888 float slots  (3.7 MB)
    //   asum : 16*15*32            =     7,680
    //   sc2  : 32
    //   Cbf  : 32*512 ushort       =     8,192 float slots
    float* ws = (float*)d_ws;
    ushort* xcp = (ushort*)ws;
    float* x2p = ws + 3735552;
    ushort* At = (ushort*)(x2p + 233472);
    float* asum_part = x2p + 233472 + 933888;
    float* sc2 = asum_part + 7680;
    ushort* Cbf = (ushort*)(sc2 + KK);

    k0_prep<<<dim3(1), dim3(256), 0, stream>>>(Cw, scale, Cbf, sc2);
    k1_gemm1<<<dim3(BB * NDR1 * NNR1), dim3(256), 0, stream>>>(X, Cbf, xcp, x2p);
    k2_softmax<<<dim3(BB * NCH2), dim3(256), 0, stream>>>(xcp, x2p, scale, sc2, At, asum_part);
    k3_gemm2<<<dim3(BB * NDR3), dim3(256), 0, stream>>>(X, At, asum_part, Cw, E);
}

// Round 14
// 52.601 us; speedup vs baseline: 1.8023x; 1.8023x over previous
//
#include <hip/hip_runtime.h>
#include <hip/hip_bf16.h>

// Problem constants:
//   X: (B=16, D=512, 60, 60) fp32 -> N = 3600
//   codewords: (K=32, D=512) fp32, scale: (K=32,) fp32
//   out E: (B, K, D) fp32
constexpr int BB = 16;
constexpr int DD = 512;
constexpr int NN = 3600;
constexpr int KK = 32;
constexpr int SB = 29;     // 128-n windows per batch
constexpr int WIN = 128;

typedef __attribute__((ext_vector_type(8))) short short8;
typedef __attribute__((ext_vector_type(4))) float f32x4;

__device__ inline unsigned bf16pack(float a, float b) {
    unsigned ia = __float_as_uint(a), ib = __float_as_uint(b);
    ia = (ia + 0x7fffu + ((ia >> 16) & 1u)) >> 16;          // RNE to bf16
    ib = (ib + 0x7fffu + ((ib >> 16) & 1u)) & 0xffff0000u;
    return ia | ib;
}

// ---------------------------------------------------------------------------
// K0: Cbf[k][d] = bf16(Cw[k][d]);  sc2[k] = scale[k]*sum_d C[k,d]^2
// ---------------------------------------------------------------------------
__global__ __launch_bounds__(256) void k0_prep(const float* __restrict__ Cw,
                                               const float* __restrict__ scale,
                                               ushort* __restrict__ Cbf,
                                               float* __restrict__ sc2) {
    __shared__ float buf[8][32];
    const int t = threadIdx.x;
    const int k = t & 31;
    const int h = t >> 5;   // 0..7, 64 d's each
    const float4* row = reinterpret_cast<const float4*>(Cw + k * DD + h * 64);
    uint2* crow = reinterpret_cast<uint2*>(Cbf + k * DD + h * 64);
    float s = 0.f;
#pragma unroll
    for (int j = 0; j < 16; ++j) {
        float4 v = row[j];
        crow[j] = make_uint2(bf16pack(v.x, v.y), bf16pack(v.z, v.w));
        s += v.x * v.x + v.y * v.y + v.z * v.z + v.w * v.w;
    }
    buf[h][k] = s;
    __syncthreads();
    if (t < 32) {
        float tot = 0.f;
#pragma unroll
        for (int j = 0; j < 8; ++j) tot += buf[j][t];
        sc2[t] = scale[t] * tot;
    }
}

// ---------------------------------------------------------------------------
// KF: fused GEMM1 + softmax + GEMM2, async-pipelined staging (R9 structure).
// Grid: B*SB = 464 blocks x 512 threads (8 waves), 1 block/CU (145 KB LDS).
// 4 chunks of 128 d: chunk c+1's global loads stay IN FLIGHT across a raw
// s_barrier (lgkmcnt-only) -> counted vmcnt instead of the __syncthreads
// vmcnt(0) drain. Phase A reads A-frags as swizzled LDS column u16s; phase B
// re-reads the same tile row-wise (b128). Out: Ep bf16 partials + asum.
// ---------------------------------------------------------------------------
__global__ __launch_bounds__(512) void kf_fused(const float* __restrict__ X,
                                                const ushort* __restrict__ Cbf,
                                                const float* __restrict__ scale,
                                                const float* __restrict__ sc2,
                                                ushort* __restrict__ Epb,
                                                float* __restrict__ asum_part) {
    __shared__ ushort tile[DD * WIN];     // 128 KB, XOR-swizzled
    __shared__ ushort As2[KK * WIN];      // 8 KB, same swizzle per k-row
    __shared__ float x2part[16][WIN];     // 8 KB
    __shared__ float x2s[WIN];
    __shared__ float asw[8][KK];

    const int t = threadIdx.x;
    const int w = t >> 6;     // wave 0..7
    const int l = t & 63;
    const int q = l >> 4;     // 0..3
    const int r = l & 15;     // 0..15
    const int ng = t & 31;    // staging n-group (4 n)
    const int dgs = t >> 5;   // staging d-subrow 0..15
    const int b = blockIdx.x / SB;
    const int sb = blockIdx.x % SB;
    const int n0 = sb * WIN;
    const float* Xb = X + (size_t)b * DD * NN;
    const ushort* cb0 = Cbf + r * DD + q * 8;
    const ushort* cb1 = cb0 + 16 * DD;

    int nst = n0 + ng * 4;
    if (nst > NN - 4) nst = NN - 4;
    const float* xsrc = Xb + nst;

    const int nloc = w * 16 + r;          // phase-A A-frag row (n)
    f32x4 a0 = {0.f, 0.f, 0.f, 0.f};
    f32x4 a1 = {0.f, 0.f, 0.f, 0.f};
    float x2loc[4] = {0.f, 0.f, 0.f, 0.f};

    float4 bufA[8], bufB[8];
#pragma unroll
    for (int i = 0; i < 8; ++i)
        bufA[i] = *reinterpret_cast<const float4*>(xsrc + (size_t)(dgs * 8 + i) * NN);

    // One chunk = 128 d rows staged + 4 MFMA steps. C-frag loads are issued
    // BEFORE the next-chunk prefetch so the MFMA's vmcnt wait (oldest-first)
    // leaves the prefetch in flight.
#define CHUNK_BODY(CURB, NXTB, C)                                              \
    {                                                                          \
        short8 cf0[4], cf1[4];                                                 \
        _Pragma("unroll")                                                      \
        for (int u = 0; u < 4; ++u) {                                          \
            cf0[u] = *reinterpret_cast<const short8*>(cb0 + ((C)*4 + u) * 32); \
            cf1[u] = *reinterpret_cast<const short8*>(cb1 + ((C)*4 + u) * 32); \
        }                                                                      \
        if ((C) < 3) {                                                         \
            _Pragma("unroll")                                                  \
            for (int i = 0; i < 8; ++i)                                        \
                NXTB[i] = *reinterpret_cast<const float4*>(                    \
                    xsrc + (size_t)(((C) + 1) * 128 + dgs * 8 + i) * NN);      \
        }                                                                      \
        _Pragma("unroll")                                                      \
        for (int i = 0; i < 8; ++i) {                                          \
            const float4 v = CURB[i];                                          \
            x2loc[0] = fmaf(v.x, v.x, x2loc[0]);                               \
            x2loc[1] = fmaf(v.y, v.y, x2loc[1]);                               \
            x2loc[2] = fmaf(v.z, v.z, x2loc[2]);                               \
            x2loc[3] = fmaf(v.w, v.w, x2loc[3]);                               \
            const int d = (C) * 128 + dgs * 8 + i;                             \
            *reinterpret_cast<uint2*>(                                         \
                &tile[d * WIN + ((ng * 4) ^ ((d & 7) << 3))]) =                \
                make_uint2(bf16pack(v.x, v.y), bf16pack(v.z, v.w));            \
        }                                                                      \
        asm volatile("s_waitcnt lgkmcnt(0)" ::: "memory");                     \
        __builtin_amdgcn_s_barrier();                                          \
        __builtin_amdgcn_sched_barrier(0);                                     \
        _Pragma("unroll")                                                      \
        for (int u = 0; u < 4; ++u) {                                          \
            const int s = (C) * 4 + u;                                         \
            union { short8 s8; ushort us[8]; } af;                             \
            _Pragma("unroll")                                                  \
            for (int jj = 0; jj < 8; ++jj)                                     \
                af.us[jj] = tile[(s * 32 + q * 8 + jj) * WIN + (nloc ^ (jj << 3))]; \
            a0 = __builtin_amdgcn_mfma_f32_16x16x32_bf16(af.s8, cf0[u], a0, 0, 0, 0); \
            a1 = __builtin_amdgcn_mfma_f32_16x16x32_bf16(af.s8, cf1[u], a1, 0, 0, 0); \
        }                                                                      \
    }

    CHUNK_BODY(bufA, bufB, 0)
    CHUNK_BODY(bufB, bufA, 1)
    CHUNK_BODY(bufA, bufB, 2)
    CHUNK_BODY(bufB, bufA, 3)
#undef CHUNK_BODY

    // ---- x2 reduction (fp32 exact) ----
    *reinterpret_cast<f32x4*>(&x2part[dgs][ng * 4]) =
        (f32x4){x2loc[0], x2loc[1], x2loc[2], x2loc[3]};
    __syncthreads();   // no vmem in flight now -> drain harmless
    if (t < WIN) {
        float s = 0.f;
#pragma unroll
        for (int dg = 0; dg < 16; ++dg) s += x2part[dg][t];
        x2s[t] = s;
    }
    __syncthreads();

    // ---- softmax (lane (q,r): n = w*16 + 4q + i, k = r / r+16) ----
    const float sk0 = scale[r], sk1 = scale[r + 16];
    const float sq0 = sc2[r],  sq1 = sc2[r + 16];
    float e0v[4], e1v[4];
    float as0 = 0.f, as1 = 0.f;
#pragma unroll
    for (int i = 0; i < 4; ++i) {
        const float x2v = x2s[w * 16 + 4 * q + i];
        float sl0 = fmaf(sk0, x2v, sq0) - 2.f * sk0 * a0[i];
        float sl1 = fmaf(sk1, x2v, sq1) - 2.f * sk1 * a1[i];
        float m = fmaxf(sl0, sl1);
        m = fmaxf(m, __shfl_xor(m, 1));
        m = fmaxf(m, __shfl_xor(m, 2));
        m = fmaxf(m, __shfl_xor(m, 4));
        m = fmaxf(m, __shfl_xor(m, 8));
        float e0 = __expf(sl0 - m), e1 = __expf(sl1 - m);
        float ssum = e0 + e1;
        ssum += __shfl_xor(ssum, 1);
        ssum += __shfl_xor(ssum, 2);
        ssum += __shfl_xor(ssum, 4);
        ssum += __shfl_xor(ssum, 8);
        const float inv = 1.f / ssum;
        e0 *= inv; e1 *= inv;
        if (n0 + w * 16 + 4 * q + i >= NN) { e0 = 0.f; e1 = 0.f; }
        e0v[i] = e0; e1v[i] = e1;
        as0 += e0; as1 += e1;
    }
    *reinterpret_cast<uint2*>(&As2[r * WIN + ((w * 16 + 4 * q) ^ ((r & 7) << 3))]) =
        make_uint2(bf16pack(e0v[0], e0v[1]), bf16pack(e0v[2], e0v[3]));
    *reinterpret_cast<uint2*>(&As2[(r + 16) * WIN + ((w * 16 + 4 * q) ^ ((r & 7) << 3))]) =
        make_uint2(bf16pack(e1v[0], e1v[1]), bf16pack(e1v[2], e1v[3]));

    as0 += __shfl_xor(as0, 16); as0 += __shfl_xor(as0, 32);
    as1 += __shfl_xor(as1, 16); as1 += __shfl_xor(as1, 32);
    if (l < 16) { asw[w][r] = as0; asw[w][r + 16] = as1; }
    __syncthreads();
    if (t < KK) {
        float s = 0.f;
#pragma unroll
        for (int jw = 0; jw < 8; ++jw) s += asw[jw][t];
        asum_part[((size_t)b * SB + sb) * KK + t] = s;
    }

    // ---- phase B: GEMM2 from the tile; wave w owns d in [w*64, w*64+64) ----
    short8 bfr0[4], bfr1[4];
#pragma unroll
    for (int step = 0; step < 4; ++step) {
        bfr0[step] = *reinterpret_cast<const short8*>(
            &As2[r * WIN + ((step * 32 + q * 8) ^ ((r & 7) << 3))]);
        bfr1[step] = *reinterpret_cast<const short8*>(
            &As2[(r + 16) * WIN + ((step * 32 + q * 8) ^ ((r & 7) << 3))]);
    }

    f32x4 acc[4][2];
#pragma unroll
    for (int df = 0; df < 4; ++df) {
        acc[df][0] = (f32x4){0.f, 0.f, 0.f, 0.f};
        acc[df][1] = (f32x4){0.f, 0.f, 0.f, 0.f};
    }

#pragma unroll
    for (int df = 0; df < 4; ++df) {
        const int d = w * 64 + df * 16 + r;   // A-frag row; d&7 == r&7
#pragma unroll
        for (int step = 0; step < 4; ++step) {
            const short8 xa = *reinterpret_cast<const short8*>(
                &tile[d * WIN + ((step * 32 + q * 8) ^ ((d & 7) << 3))]);
            acc[df][0] = __builtin_amdgcn_mfma_f32_16x16x32_bf16(
                xa, bfr0[step], acc[df][0], 0, 0, 0);
            acc[df][1] = __builtin_amdgcn_mfma_f32_16x16x32_bf16(
                xa, bfr1[step], acc[df][1], 0, 0, 0);
        }
    }

    // ---- store Ep partial (bf16): D-frag rows q*4+i are d-contiguous ----
    ushort* ep = Epb + (size_t)(b * SB + sb) * KK * DD;
#pragma unroll
    for (int df = 0; df < 4; ++df) {
#pragma unroll
        for (int kf = 0; kf < 2; ++kf) {
            const int k = kf * 16 + r;
            const int d = w * 64 + df * 16 + q * 4;
            const f32x4 v = acc[df][kf];
            *reinterpret_cast<uint2*>(ep + (size_t)k * DD + d) =
                make_uint2(bf16pack(v[0], v[1]), bf16pack(v[2], v[3]));
        }
    }
}

// ---------------------------------------------------------------------------
// K3: E[b,k,d] = sum_sb bf16(Ep[b,sb,k,d]) - Asum[b,k]*C[k,d]
// Grid: B*K = 512 blocks x 128 threads; lane owns 4 d via one uint2 per
// split (1 KB per wave-instruction, fully coalesced).
// ---------------------------------------------------------------------------
__global__ __launch_bounds__(128) void k3_final(const ushort* __restrict__ Epb,
                                                const float* __restrict__ asum_part,
                                                const float* __restrict__ Cw,
                                                float* __restrict__ E) {
    const int t = threadIdx.x;
    const int b = blockIdx.x >> 5, k = blockIdx.x & 31;

    float asum = 0.f;
#pragma unroll
    for (int sb = 0; sb < SB; ++sb)   // uniform -> scalar loads
        asum += asum_part[((size_t)b * SB + sb) * KK + k];

    const int d = t * 4;
    float s0 = 0.f, s1 = 0.f, s2 = 0.f, s3 = 0.f;
    const ushort* base = Epb + ((size_t)b * SB * KK + k) * DD + d;
#pragma unroll 4
    for (int sb = 0; sb < SB; ++sb) {
        const uint2 u = *reinterpret_cast<const uint2*>(base + (size_t)sb * KK * DD);
        s0 += __uint_as_float(u.x << 16);
        s1 += __uint_as_float(u.x & 0xffff0000u);
        s2 += __uint_as_float(u.y << 16);
        s3 += __uint_as_float(u.y & 0xffff0000u);
    }
    const float4 c = *reinterpret_cast<const float4*>(Cw + k * DD + d);
    float4 o;
    o.x = s0 - asum * c.x;
    o.y = s1 - asum * c.y;
    o.z = s2 - asum * c.z;
    o.w = s3 - asum * c.w;
    *reinterpret_cast<float4*>(E + ((size_t)b * KK + k) * DD + d) = o;
}

// ---------------------------------------------------------------------------
extern "C" void kernel_launch(void* const* d_in, const int* in_sizes, int n_in,
                              void* d_out, int out_size, void* d_ws, size_t ws_size,
                              hipStream_t stream) {
    const float* X     = (const float*)d_in[0];
    const float* Cw    = (const float*)d_in[1];
    const float* scale = (const float*)d_in[2];
    float* E = (float*)d_out;

    // ws layout:
    //   Epb       : 16*29*32*512 ushort = 7,602,176 u16 (~15.2 MB)
    //   asum_part : 464*32 float
    //   sc2       : 32 float
    //   Cbf       : 32*512 ushort
    float* ws = (float*)d_ws;
    ushort* Epb = (ushort*)ws;
    float* asum_part = ws + (size_t)BB * SB * KK * DD / 2;
    float* sc2 = asum_part + (size_t)BB * SB * KK;
    ushort* Cbf = (ushort*)(sc2 + KK);

    k0_prep<<<dim3(1), dim3(256), 0, stream>>>(Cw, scale, Cbf, sc2);
    kf_fused<<<dim3(BB * SB), dim3(512), 0, stream>>>(X, Cbf, scale, sc2, Epb, asum_part);
    k3_final<<<dim3(BB * KK), dim3(128), 0, stream>>>(Epb, asum_part, Cw, E);
}